// Round 4
// baseline (141.155 us; speedup 1.0000x reference)
//
#include <hip/hip_runtime.h>

typedef __attribute__((ext_vector_type(8))) short bf16x8;
typedef __attribute__((ext_vector_type(4))) float f32x4;
typedef __attribute__((ext_vector_type(2))) unsigned int u32x2;

#define XP_BYTES (2048 * 3364 * 2)   // padded x, bf16: 32*64 planes of 58x58
#define BSTG_OFF XP_BYTES            // Weff: 512 x 1024 bf16 = 1 MB, n-major

static __device__ __forceinline__ unsigned short f2bf(float v) {
    unsigned int u = __builtin_bit_cast(unsigned int, v);
    u += 0x7fffu + ((u >> 16) & 1u);
    return (unsigned short)(u >> 16);
}

// ---------------------------------------------------------------------------
// Prep: (a) pad+convert x to bf16 58x58 planes; (b) fold Hadamard transforms
// into direct-conv weights, plain n-major layout weff[n*1024 + c*16 + b*4 + a].
// ---------------------------------------------------------------------------
__global__ __launch_bounds__(256) void prep(const float* __restrict__ x,
                                            const float* __restrict__ w,
                                            unsigned char* __restrict__ ws)
{
    int bid = blockIdx.x;
    if (bid < 2048) {
        const float* src = x + (size_t)bid * 3136;
        unsigned int* dst = (unsigned int*)ws + (size_t)bid * 1682;
        for (int s = threadIdx.x; s < 1682; s += 256) {
            int r = s / 29, p = s - r * 29;
            float v0 = 0.f, v1 = 0.f;
            if (r >= 1 && r <= 56) {
                const float* row = src + (r - 1) * 56;
                if (p >= 1)  v0 = row[2 * p - 1];
                if (p <= 27) v1 = row[2 * p];
            }
            dst[s] = (unsigned int)f2bf(v0) | ((unsigned int)f2bf(v1) << 16);
        }
        return;
    }
    int idx = (bid - 2048) * 256 + threadIdx.x;   // (o,c) pair
    if (idx >= 128 * 64) return;
    int o = idx >> 6, c = idx & 63;
    const bool v2 = (o >= 64);
    const float Hm[4][4]  = {{1,1,1,1},{1,-1,1,-1},{1,1,-1,-1},{1,-1,-1,1}};
    const float H2m[4][4] = {{1,-1,1,-1},{1,1,1,1},{1,1,-1,-1},{1,-1,-1,1}};

    float wv[4][4];
    #pragma unroll
    for (int i = 0; i < 4; ++i)
        #pragma unroll
        for (int j = 0; j < 4; ++j)
            wv[i][j] = w[((o * 64 + c) * 4 + i) * 4 + j];

    float FA[4][4], FB[4][4], G[2][4];
    #pragma unroll
    for (int a = 0; a < 4; ++a)
        #pragma unroll
        for (int i = 0; i < 4; ++i) {
            FA[a][i] = v2 ? H2m[a][i] : Hm[i][a];
            FB[a][i] = v2 ? H2m[a][i] : Hm[a][i];
        }
    #pragma unroll
    for (int p = 0; p < 2; ++p)
        #pragma unroll
        for (int i = 0; i < 4; ++i)
            G[p][i] = 0.25f * (v2 ? H2m[p + 1][i] : Hm[p + 1][i]);

    unsigned short* weff = (unsigned short*)(ws + BSTG_OFF);
    #pragma unroll
    for (int P = 0; P < 2; ++P)
    #pragma unroll
    for (int Q = 0; Q < 2; ++Q) {
        int nrow = o * 4 + P * 2 + Q;
        #pragma unroll
        for (int b = 0; b < 4; ++b)
        #pragma unroll
        for (int a = 0; a < 4; ++a) {
            float s = 0.f;
            #pragma unroll
            for (int i = 0; i < 4; ++i) {
                float sj = 0.f;
                #pragma unroll
                for (int j = 0; j < 4; ++j)
                    sj += FB[b][j] * G[Q][j] * wv[i][j];
                s += G[P][i] * FA[a][i] * sj;
            }
            weff[(size_t)nrow * 1024 + c * 16 + b * 4 + a] = f2bf(s);
        }
    }
}

// ---------------------------------------------------------------------------
// Main: ZERO-LDS barrier-free GEMM. Both MFMA operand fragments are loaded
// directly from global (A: two 8B rows of the padded image; B: 16B of n-major
// Weff). 2-deep manual fragment pipeline -> counted vmcnt, no drains.
// Block = 4 independent waves: same 64-row A panel (L1 reuse), 4 N-slices.
// M=25088 (392x64), N=512 (4 ng x 4 wn x 32), K=1024 (32 ks x 32).
// ---------------------------------------------------------------------------
__global__ __launch_bounds__(256, 4) void conv_gemm(
    const unsigned short* __restrict__ xp,
    const unsigned short* __restrict__ weff,
    const float* __restrict__ bias,
    float* __restrict__ out)
{
    __shared__ int s_pbase[64];
    __shared__ int s_obase[64];

    const int tid  = threadIdx.x;
    const int lane = tid & 63;
    const int wn   = tid >> 6;                 // 0..3
    const int bid  = blockIdx.x;
    // XCD-chunked swizzle: 1568 = 8*196; the 4 ng of one A-panel share an XCD
    const int wid = (bid & 7) * 196 + (bid >> 3);
    const int tg  = wid >> 2, ng = wid & 3;
    const int t0  = tg << 6;
    const int n0  = (ng << 7) + (wn << 5);

    if (tid < 64) {
        int t = t0 + tid;
        int nimg = t / 784, rem = t - nimg * 784;
        int h = rem / 28, w = rem - h * 28;
        s_pbase[tid] = nimg * 215296 + (2 * h) * 58 + 2 * w;   // xp elems
        s_obase[tid] = nimg * 401408 + (2 * h) * 56 + 2 * w;   // out elems
    }
    __syncthreads();

    const int g   = lane >> 4;     // k-chunk group 0..3
    const int l15 = lane & 15;

    // A: row m = fm*16+l15; k-chunk g*8 = plane (g>>1), window rows (g&1)*2.
    // byte = 2*pbase + (g>>1)*6728 + (g&1)*232 ; pair row at +116 ; ks: +13456
    unsigned int aoff[4];
    #pragma unroll
    for (int fm = 0; fm < 4; ++fm)
        aoff[fm] = (unsigned)(s_pbase[fm * 16 + l15] * 2)
                 + (unsigned)((g >> 1) * 6728 + (g & 1) * 232);
    // B: row n, 16B chunk at n*2048 + g*16 ; ks: +64
    unsigned int boff[2];
    #pragma unroll
    for (int fn = 0; fn < 2; ++fn)
        boff[fn] = (unsigned)((n0 + fn * 16 + l15) * 2048 + g * 16);

    const char* xb = (const char*)xp;
    const char* bb = (const char*)weff;

    f32x4 acc[4][2];
    #pragma unroll
    for (int i = 0; i < 4; ++i)
        #pragma unroll
        for (int j = 0; j < 2; ++j)
            acc[i][j] = (f32x4){0.f, 0.f, 0.f, 0.f};

    struct F { bf16x8 a[4]; bf16x8 b[2]; };
    union U { u32x2 h[2]; bf16x8 v; };

    auto LOADF = [&](int ks, F& f) {
        const unsigned int ao = (unsigned)ks * 13456u;
        const unsigned int bo = (unsigned)ks * 64u;
        #pragma unroll
        for (int fm = 0; fm < 4; ++fm) {
            U u;
            u.h[0] = *(const u32x2*)(xb + (aoff[fm] + ao));
            u.h[1] = *(const u32x2*)(xb + (aoff[fm] + ao + 116u));
            f.a[fm] = u.v;
        }
        #pragma unroll
        for (int fn = 0; fn < 2; ++fn)
            f.b[fn] = *(const bf16x8*)(bb + (boff[fn] + bo));
    };
    auto MFMAF = [&](F& f) {
        #pragma unroll
        for (int fm = 0; fm < 4; ++fm)
            #pragma unroll
            for (int fn = 0; fn < 2; ++fn)
                acc[fm][fn] = __builtin_amdgcn_mfma_f32_16x16x32_bf16(
                    f.a[fm], f.b[fn], acc[fm][fn], 0, 0, 0);
    };

    F fA, fB;
    LOADF(0, fA);
    for (int ks = 0; ks < 30; ks += 2) {
        LOADF(ks + 1, fB);     // in flight while fA computes
        MFMAF(fA);
        LOADF(ks + 2, fA);
        MFMAF(fB);
    }
    LOADF(31, fB);
    MFMAF(fA);
    MFMAF(fB);

    // epilogue: D col = lane&15 (n), row = g*4 + reg (m)
    #pragma unroll
    for (int fn = 0; fn < 2; ++fn) {
        int n = n0 + fn * 16 + l15;
        int o = n >> 2, P = (n >> 1) & 1, Q = n & 1;
        float bo = bias[o];
        int ooff = o * 3136 + P * 56 + Q;
        #pragma unroll
        for (int fm = 0; fm < 4; ++fm) {
            int mb = fm * 16 + (g << 2);
            #pragma unroll
            for (int r = 0; r < 4; ++r)
                out[s_obase[mb + r] + ooff] = acc[fm][fn][r] + bo;
        }
    }
}

extern "C" void kernel_launch(void* const* d_in, const int* in_sizes, int n_in,
                              void* d_out, int out_size, void* d_ws, size_t ws_size,
                              hipStream_t stream)
{
    const float* x = (const float*)d_in[0];
    const float* w = (const float*)d_in[1];
    const float* b = (const float*)d_in[2];
    float* out = (float*)d_out;
    unsigned char* ws = (unsigned char*)d_ws;

    hipLaunchKernelGGL(prep, dim3(2048 + 32), dim3(256), 0, stream, x, w, ws);
    hipLaunchKernelGGL(conv_gemm, dim3(1568), dim3(256), 0, stream,
                       (const unsigned short*)ws,
                       (const unsigned short*)(ws + BSTG_OFF), b, out);
}

// Round 5
// 119.025 us; speedup vs baseline: 1.1859x; 1.1859x over previous
//
#include <hip/hip_runtime.h>

typedef __attribute__((ext_vector_type(8))) short bf16x8;
typedef __attribute__((ext_vector_type(4))) float f32x4;
typedef __attribute__((ext_vector_type(4))) unsigned int u32x4;

#define XP_BYTES (2048 * 3364 * 2)   // padded x, bf16: 32*64 planes of 58x58
#define BSTG_OFF XP_BYTES            // Weff: 512 x 1024 bf16 = 1 MB, n-major

static __device__ __forceinline__ unsigned short f2bf(float v) {
    unsigned int u = __builtin_bit_cast(unsigned int, v);
    u += 0x7fffu + ((u >> 16) & 1u);
    return (unsigned short)(u >> 16);
}

// ---------------------------------------------------------------------------
// Prep: (a) pad+convert x to bf16 58x58 planes; (b) fold Hadamard transforms
// into direct-conv weights, n-major: weff[n'*1024 + c*16 + b*4 + a].
// ---------------------------------------------------------------------------
__global__ __launch_bounds__(256) void prep(const float* __restrict__ x,
                                            const float* __restrict__ w,
                                            unsigned char* __restrict__ ws)
{
    int bid = blockIdx.x;
    if (bid < 2048) {
        const float* src = x + (size_t)bid * 3136;
        unsigned int* dst = (unsigned int*)ws + (size_t)bid * 1682;
        for (int s = threadIdx.x; s < 1682; s += 256) {
            int r = s / 29, p = s - r * 29;
            float v0 = 0.f, v1 = 0.f;
            if (r >= 1 && r <= 56) {
                const float* row = src + (r - 1) * 56;
                if (p >= 1)  v0 = row[2 * p - 1];
                if (p <= 27) v1 = row[2 * p];
            }
            dst[s] = (unsigned int)f2bf(v0) | ((unsigned int)f2bf(v1) << 16);
        }
        return;
    }
    int idx = (bid - 2048) * 256 + threadIdx.x;   // (o,c) pair
    if (idx >= 128 * 64) return;
    int o = idx >> 6, c = idx & 63;
    const bool v2 = (o >= 64);
    const float Hm[4][4]  = {{1,1,1,1},{1,-1,1,-1},{1,1,-1,-1},{1,-1,-1,1}};
    const float H2m[4][4] = {{1,-1,1,-1},{1,1,1,1},{1,1,-1,-1},{1,-1,-1,1}};

    float wv[4][4];
    #pragma unroll
    for (int i = 0; i < 4; ++i)
        #pragma unroll
        for (int j = 0; j < 4; ++j)
            wv[i][j] = w[((o * 64 + c) * 4 + i) * 4 + j];

    float FA[4][4], FB[4][4], G[2][4];
    #pragma unroll
    for (int a = 0; a < 4; ++a)
        #pragma unroll
        for (int i = 0; i < 4; ++i) {
            FA[a][i] = v2 ? H2m[a][i] : Hm[i][a];
            FB[a][i] = v2 ? H2m[a][i] : Hm[a][i];
        }
    #pragma unroll
    for (int p = 0; p < 2; ++p)
        #pragma unroll
        for (int i = 0; i < 4; ++i)
            G[p][i] = 0.25f * (v2 ? H2m[p + 1][i] : Hm[p + 1][i]);

    unsigned short* weff = (unsigned short*)(ws + BSTG_OFF);
    #pragma unroll
    for (int P = 0; P < 2; ++P)
    #pragma unroll
    for (int Q = 0; Q < 2; ++Q) {
        int nrow = o * 4 + P * 2 + Q;
        #pragma unroll
        for (int b = 0; b < 4; ++b)
        #pragma unroll
        for (int a = 0; a < 4; ++a) {
            float s = 0.f;
            #pragma unroll
            for (int i = 0; i < 4; ++i) {
                float sj = 0.f;
                #pragma unroll
                for (int j = 0; j < 4; ++j)
                    sj += FB[b][j] * G[Q][j] * wv[i][j];
                s += G[P][i] * FA[a][i] * sj;
            }
            weff[(size_t)nrow * 1024 + c * 16 + b * 4 + a] = f2bf(s);
        }
    }
}

// ---------------------------------------------------------------------------
// Main GEMM, split-operand staging:
//   A (im2col of xp): coalesced gather -> regs -> LDS (pad-80 rows), dist-2.
//   B (Weff, L2-resident): direct global -> per-wave regs, dist-1.
// Barrier guards ONLY the A LDS tile: raw s_barrier + lgkmcnt(0) -- global
// loads stay in flight across it (counted vmcnt by compiler reg-deps).
// Block: 256 thr = 4 waves (2m x 2n), tile 128x128, BK=32, 32 K-steps.
// Per wave 64x64 out: fm4 x fn4 = 16 MFMA (16x16x32 bf16) per step.
// ---------------------------------------------------------------------------
__global__ __launch_bounds__(256) void conv_gemm(
    const unsigned short* __restrict__ xp,
    const unsigned short* __restrict__ weff,
    const float* __restrict__ bias,
    float* __restrict__ out)
{
    __shared__ __align__(16) unsigned char Abuf[2][128 * 80];  // 2 x 10KB
    __shared__ int s_pbase[128];
    __shared__ int s_obase[128];

    const int tid  = threadIdx.x;
    const int lane = tid & 63;
    const int l15  = lane & 15;
    const int g    = lane >> 4;             // k-chunk 0..3
    const int wv   = tid >> 6;
    const int wm   = wv >> 1, wn = wv & 1;  // 2 x 2 wave grid
    const int bid  = blockIdx.x;
    // XCD-chunked swizzle: 784 = 8*98; 4 n-groups of one A-panel share an XCD
    const int wid = (bid & 7) * 98 + (bid >> 3);
    const int tg  = wid >> 2, ng = wid & 3;
    const int t0  = tg << 7;
    const int n0  = (ng << 7) + (wn << 6);

    if (tid < 128) {
        int t = t0 + tid;
        int nimg = t / 784, rem = t - nimg * 784;
        int h = rem / 28, w = rem - h * 28;
        s_pbase[tid] = nimg * 215296 + (2 * h) * 58 + 2 * w;   // xp elems
        s_obase[tid] = nimg * 401408 + (2 * h) * 56 + 2 * w;   // out elems
    }
    __syncthreads();

    // A-gather: one (tile, channel-of-2) pair per thread
    const int tl = tid >> 1, cc = tid & 1;
    const int ebase0 = s_pbase[tl] + cc * 3364;
    const int awr = tl * 80 + cc * 32;      // LDS write offset (pad-80 rows)

    int abase[4];
    #pragma unroll
    for (int fm = 0; fm < 4; ++fm)
        abase[fm] = (wm * 64 + fm * 16 + l15) * 80 + g * 16;
    unsigned int boff[4];
    #pragma unroll
    for (int fn = 0; fn < 4; ++fn)
        boff[fn] = (unsigned)((n0 + fn * 16 + l15) * 2048 + g * 16);

    const char* bb = (const char*)weff;

    f32x4 acc[4][4];
    #pragma unroll
    for (int i = 0; i < 4; ++i)
        #pragma unroll
        for (int j = 0; j < 4; ++j)
            acc[i][j] = (f32x4){0.f, 0.f, 0.f, 0.f};

    unsigned int Ar0[8], Ar1[8];
    bf16x8 bg0[4], bg1[4];

    auto GATHER_A = [&](int k, unsigned int* A) {
        const unsigned short* p = xp + (ebase0 + k * 6728);   // k*2 planes
        #pragma unroll
        for (int b = 0; b < 4; ++b) {
            A[b * 2]     = *(const unsigned int*)(p + b * 58);
            A[b * 2 + 1] = *(const unsigned int*)(p + b * 58 + 2);
        }
    };
    auto STAGE_A = [&](const unsigned int* A, int slot) {
        u32x4 q0 = {A[0], A[1], A[2], A[3]};
        u32x4 q1 = {A[4], A[5], A[6], A[7]};
        *(u32x4*)(Abuf[slot] + awr)      = q0;
        *(u32x4*)(Abuf[slot] + awr + 16) = q1;
    };
    auto LOAD_B = [&](int k, bf16x8* bg) {
        const char* q = bb + (unsigned)k * 64u;
        #pragma unroll
        for (int fn = 0; fn < 4; ++fn)
            bg[fn] = *(const bf16x8*)(q + boff[fn]);
    };
    auto MFMA_STEP = [&](int slot, const bf16x8* bg) {
        bf16x8 af[4];
        #pragma unroll
        for (int fm = 0; fm < 4; ++fm)
            af[fm] = *(const bf16x8*)(Abuf[slot] + abase[fm]);
        #pragma unroll
        for (int fm = 0; fm < 4; ++fm)
            #pragma unroll
            for (int fn = 0; fn < 4; ++fn)
                acc[fm][fn] = __builtin_amdgcn_mfma_f32_16x16x32_bf16(
                    af[fm], bg[fn], acc[fm][fn], 0, 0, 0);
    };

    // prologue: A(0),A(1) in flight; B(0) in flight; stage A(0)
    GATHER_A(0, Ar0);
    LOAD_B(0, bg0);
    GATHER_A(1, Ar1);
    STAGE_A(Ar0, 0);
    asm volatile("s_waitcnt lgkmcnt(0)" ::: "memory");
    __builtin_amdgcn_s_barrier();
    __builtin_amdgcn_sched_barrier(0);

    #pragma unroll
    for (int k = 0; k < 32; ++k) {
        // A(k+2) -> reg set k&1 (A(k) already staged at step k-1)
        if (k < 30) GATHER_A(k + 2, (k & 1) ? Ar1 : Ar0);
        // B(k+1) -> reg set (k+1)&1
        if (k < 31) LOAD_B(k + 1, (k & 1) ? bg0 : bg1);
        // compute step k from LDS slot k&1 and B set k&1
        MFMA_STEP(k & 1, (k & 1) ? bg1 : bg0);
        if (k < 31) {
            // write A(k+1) (gathered at k-1 into set (k+1)&1) into slot (k+1)&1
            STAGE_A((k & 1) ? Ar0 : Ar1, (k + 1) & 1);
            asm volatile("s_waitcnt lgkmcnt(0)" ::: "memory");
            __builtin_amdgcn_s_barrier();      // NO vmcnt drain: prefetches fly on
            __builtin_amdgcn_sched_barrier(0);
        }
    }

    // epilogue: D col = lane&15 (n), row = g*4 + reg (m)
    #pragma unroll
    for (int fn = 0; fn < 4; ++fn) {
        int n = n0 + fn * 16 + l15;
        int o = n >> 2, P = (n >> 1) & 1, Q = n & 1;
        float bo = bias[o];
        int ooff = o * 3136 + P * 56 + Q;
        #pragma unroll
        for (int fm = 0; fm < 4; ++fm) {
            int mb = wm * 64 + fm * 16 + (g << 2);
            #pragma unroll
            for (int r = 0; r < 4; ++r)
                out[s_obase[mb + r] + ooff] = acc[fm][fn][r] + bo;
        }
    }
}

extern "C" void kernel_launch(void* const* d_in, const int* in_sizes, int n_in,
                              void* d_out, int out_size, void* d_ws, size_t ws_size,
                              hipStream_t stream)
{
    const float* x = (const float*)d_in[0];
    const float* w = (const float*)d_in[1];
    const float* b = (const float*)d_in[2];
    float* out = (float*)d_out;
    unsigned char* ws = (unsigned char*)d_ws;

    hipLaunchKernelGGL(prep, dim3(2048 + 32), dim3(256), 0, stream, x, w, ws);
    hipLaunchKernelGGL(conv_gemm, dim3(784), dim3(256), 0, stream,
                       (const unsigned short*)ws,
                       (const unsigned short*)(ws + BSTG_OFF), b, out);
}

// Round 6
// 89.719 us; speedup vs baseline: 1.5733x; 1.3266x over previous
//
#include <hip/hip_runtime.h>

typedef __attribute__((ext_vector_type(8))) short bf16x8;
typedef __attribute__((ext_vector_type(4))) float f32x4;
typedef __attribute__((ext_vector_type(4))) unsigned int u32x4;

#define XP_BYTES (2048 * 3364 * 2)   // padded x, bf16: 32*64 planes of 58x58
#define BSTG_OFF XP_BYTES            // 13,778,944 = 841*16384 (16KB aligned)
// Weff packed: 16 panels of [512 n][64 k'] bf16, pre-XOR-swizzled. 1 MB.

static __device__ __forceinline__ unsigned short f2bf(float v) {
    unsigned int u = __builtin_bit_cast(unsigned int, v);
    u += 0x7fffu + ((u >> 16) & 1u);
    return (unsigned short)(u >> 16);
}

static __device__ __forceinline__ void gload_lds16(const void* g, void* l) {
    __builtin_amdgcn_global_load_lds(
        (const __attribute__((address_space(1))) void*)g,
        (__attribute__((address_space(3))) void*)l, 16, 0, 0);
}

// ---------------------------------------------------------------------------
// Prep: (a) pad+convert x to bf16 58x58 planes; (b) fold Hadamard transforms
// into weights, packed [kstep][n][64k'] with the read-side XOR swizzle
// pre-applied (so global_load_lds can copy linearly).
// ---------------------------------------------------------------------------
__global__ __launch_bounds__(256) void prep(const float* __restrict__ x,
                                            const float* __restrict__ w,
                                            unsigned char* __restrict__ ws)
{
    int bid = blockIdx.x;
    if (bid < 2048) {
        const float* src = x + (size_t)bid * 3136;
        unsigned int* dst = (unsigned int*)ws + (size_t)bid * 1682;
        for (int s = threadIdx.x; s < 1682; s += 256) {
            int r = s / 29, p = s - r * 29;
            float v0 = 0.f, v1 = 0.f;
            if (r >= 1 && r <= 56) {
                const float* row = src + (r - 1) * 56;
                if (p >= 1)  v0 = row[2 * p - 1];
                if (p <= 27) v1 = row[2 * p];
            }
            dst[s] = (unsigned int)f2bf(v0) | ((unsigned int)f2bf(v1) << 16);
        }
        return;
    }
    int idx = (bid - 2048) * 256 + threadIdx.x;   // (o,c) pair
    if (idx >= 128 * 64) return;
    int o = idx >> 6, c = idx & 63;
    const bool v2 = (o >= 64);
    const float Hm[4][4]  = {{1,1,1,1},{1,-1,1,-1},{1,1,-1,-1},{1,-1,-1,1}};
    const float H2m[4][4] = {{1,-1,1,-1},{1,1,1,1},{1,1,-1,-1},{1,-1,-1,1}};

    float wv[4][4];
    #pragma unroll
    for (int i = 0; i < 4; ++i)
        #pragma unroll
        for (int j = 0; j < 4; ++j)
            wv[i][j] = w[((o * 64 + c) * 4 + i) * 4 + j];

    float FA[4][4], FB[4][4], G[2][4];
    #pragma unroll
    for (int a = 0; a < 4; ++a)
        #pragma unroll
        for (int i = 0; i < 4; ++i) {
            FA[a][i] = v2 ? H2m[a][i] : Hm[i][a];
            FB[a][i] = v2 ? H2m[a][i] : Hm[a][i];
        }
    #pragma unroll
    for (int p = 0; p < 2; ++p)
        #pragma unroll
        for (int i = 0; i < 4; ++i)
            G[p][i] = 0.25f * (v2 ? H2m[p + 1][i] : Hm[p + 1][i]);

    unsigned char* bstage = ws + BSTG_OFF;
    #pragma unroll
    for (int P = 0; P < 2; ++P)
    #pragma unroll
    for (int Q = 0; Q < 2; ++Q) {
        int n = o * 4 + P * 2 + Q;
        #pragma unroll
        for (int b = 0; b < 4; ++b)
        #pragma unroll
        for (int a = 0; a < 4; ++a) {
            float s = 0.f;
            #pragma unroll
            for (int i = 0; i < 4; ++i) {
                float sj = 0.f;
                #pragma unroll
                for (int j = 0; j < 4; ++j)
                    sj += FB[b][j] * G[Q][j] * wv[i][j];
                s += G[P][i] * FA[a][i] * sj;
            }
            int kg = c * 16 + b * 4 + a;           // global k
            int p  = kg >> 6, kk = kg & 63;        // panel, k-in-panel
            int byte = (n * 128 + kk * 2) ^ ((n & 7) << 4);   // pre-swizzle
            *(unsigned short*)(bstage + p * 65536 + byte) = f2bf(s);
        }
    }
}

// ---------------------------------------------------------------------------
// Main GEMM. M=25088 (196x128), N=512 (4x128), K=1024 (16 steps x 64).
// 256 thr = 4 waves (2m x 2n); wave = 64m x 64n (fm4 x fn4), 32 MFMA/step.
// A: coalesced gather (lane-consecutive tiles) -> regs (dist 2) -> swizzled
//    LDS rows of 128B. B: global_load_lds from pre-swizzled packed panels.
// Raw s_barrier + counted vmcnt: prefetches stay in flight across barriers.
// ---------------------------------------------------------------------------
__global__ __launch_bounds__(256, 2) void conv_gemm(
    const unsigned short* __restrict__ xp,
    const unsigned char* __restrict__ bws,
    const float* __restrict__ bias,
    float* __restrict__ out)
{
    __shared__ __align__(16) unsigned char Abuf[2][16384];
    __shared__ __align__(16) unsigned char Bbuf[2][16384];
    __shared__ int s_pbase[128];
    __shared__ int s_obase[128];

    const int tid  = threadIdx.x;
    const int lane = tid & 63;
    const int l15  = lane & 15;
    const int g    = lane >> 4;
    const int wv   = tid >> 6;
    const int wm   = wv >> 1, wn = wv & 1;
    const int bid  = blockIdx.x;
    // XCD-chunked swizzle: 784 = 8*98; the 4 n-groups of a panel share an XCD
    const int wid = (bid & 7) * 98 + (bid >> 3);
    const int tg  = wid >> 2, ng = wid & 3;
    const int t0  = tg << 7;
    const int n0g = ng << 7;

    if (tid < 128) {
        int t = t0 + tid;
        int nimg = t / 784, rem = t - nimg * 784;
        int h = rem / 28, w = rem - h * 28;
        s_pbase[tid] = nimg * 215296 + (2 * h) * 58 + 2 * w;   // xp elems
        s_obase[tid] = nimg * 401408 + (2 * h) * 56 + 2 * w;   // out elems
    }
    __syncthreads();

    // A-gather: thread -> (tile t, chalf). Lane-consecutive tiles!
    const int t     = tid & 127;
    const int chalf = tid >> 7;
    const int ebase0 = s_pbase[t] + chalf * 6728;   // + 2 planes if chalf

    // A ds_write offsets: 64B chunk at row t, col chalf*64, XOR-swizzled
    int wbyte[4];
    #pragma unroll
    for (int q = 0; q < 4; ++q)
        wbyte[q] = (t * 128 + chalf * 64 + q * 16) ^ ((t & 7) << 4);

    // fragment read bases; row&7 == l15&7 for all frags
    const int fswz = (l15 & 7) << 4;
    int abase[4], bbase[4];
    #pragma unroll
    for (int fm = 0; fm < 4; ++fm)
        abase[fm] = (wm * 64 + fm * 16 + l15) * 128 + g * 16;
    #pragma unroll
    for (int fn = 0; fn < 4; ++fn)
        bbase[fn] = (wn * 64 + fn * 16 + l15) * 128 + g * 16;

    f32x4 acc[4][4];
    #pragma unroll
    for (int i = 0; i < 4; ++i)
        #pragma unroll
        for (int j = 0; j < 4; ++j)
            acc[i][j] = (f32x4){0.f, 0.f, 0.f, 0.f};

    unsigned int Ar0[16], Ar1[16];

    auto GATHER_A = [&](int k, unsigned int* A) {
        const unsigned short* p = xp + (ebase0 + k * 13456);
        #pragma unroll
        for (int cp = 0; cp < 2; ++cp)
            #pragma unroll
            for (int b = 0; b < 4; ++b) {
                const unsigned short* q = p + cp * 3364 + b * 58;
                A[cp * 8 + b * 2]     = *(const unsigned int*)(q);
                A[cp * 8 + b * 2 + 1] = *(const unsigned int*)(q + 2);
            }
    };
    auto STAGE_A = [&](const unsigned int* A, int buf) {
        #pragma unroll
        for (int q = 0; q < 4; ++q) {
            u32x4 v = {A[q * 4], A[q * 4 + 1], A[q * 4 + 2], A[q * 4 + 3]};
            *(u32x4*)(Abuf[buf] + wbyte[q]) = v;
        }
    };
    auto LOAD_B = [&](int k, int buf) {
        const unsigned char* gsrc = bws + (size_t)k * 65536 + n0g * 128
                                  + wv * 4096 + lane * 16;
        #pragma unroll
        for (int q = 0; q < 4; ++q)
            gload_lds16(gsrc + q * 1024, &Bbuf[buf][wv * 4096 + q * 1024]);
        __builtin_amdgcn_sched_barrier(0);   // pin B-issue before A-gathers
    };
    auto MFMA_STEP = [&](int buf) {
        const unsigned char* Ab = Abuf[buf];
        const unsigned char* Bb = Bbuf[buf];
        __builtin_amdgcn_s_setprio(1);
        #pragma unroll
        for (int ks = 0; ks < 2; ++ks) {
            bf16x8 af[4], bg[4];
            #pragma unroll
            for (int fm = 0; fm < 4; ++fm)
                af[fm] = *(const bf16x8*)(Ab + ((abase[fm] | (ks << 6)) ^ fswz));
            #pragma unroll
            for (int fn = 0; fn < 4; ++fn)
                bg[fn] = *(const bf16x8*)(Bb + ((bbase[fn] | (ks << 6)) ^ fswz));
            #pragma unroll
            for (int fm = 0; fm < 4; ++fm)
                #pragma unroll
                for (int fn = 0; fn < 4; ++fn)
                    acc[fm][fn] = __builtin_amdgcn_mfma_f32_16x16x32_bf16(
                        af[fm], bg[fn], acc[fm][fn], 0, 0, 0);
        }
        __builtin_amdgcn_s_setprio(0);
    };

    // prologue: B(0) -> LDS0; A(0),A(1) -> regs; stage A(0) -> LDS0
    LOAD_B(0, 0);
    GATHER_A(0, Ar0);
    GATHER_A(1, Ar1);
    STAGE_A(Ar0, 0);                          // compiler: vmcnt(16) for Ar0
    asm volatile("s_waitcnt lgkmcnt(0) vmcnt(16)" ::: "memory");  // B0 landed
    __builtin_amdgcn_s_barrier();
    __builtin_amdgcn_sched_barrier(0);

    // K-steps: at step K compute buf K&1; prefetch B(K+1)->LDS, A(K+2)->regs,
    // stage A(K+1). vmcnt(16) at the barrier leaves A(K+2) in flight.
#define STEP(K, ARG, ARS, DOB, DOG, DOS)                                   \
    do {                                                                   \
        if (DOB) LOAD_B((K) + 1, ((K) + 1) & 1);                           \
        if (DOG) GATHER_A((K) + 2, ARG);                                   \
        MFMA_STEP((K) & 1);                                                \
        if (DOS) {                                                         \
            STAGE_A(ARS, ((K) + 1) & 1);                                   \
            if (DOG) asm volatile("s_waitcnt lgkmcnt(0) vmcnt(16)" ::: "memory"); \
            else     asm volatile("s_waitcnt lgkmcnt(0) vmcnt(0)"  ::: "memory"); \
            __builtin_amdgcn_s_barrier();                                  \
            __builtin_amdgcn_sched_barrier(0);                             \
        }                                                                  \
    } while (0)

    STEP(0,  Ar0, Ar1, 1, 1, 1);
    STEP(1,  Ar1, Ar0, 1, 1, 1);
    STEP(2,  Ar0, Ar1, 1, 1, 1);
    STEP(3,  Ar1, Ar0, 1, 1, 1);
    STEP(4,  Ar0, Ar1, 1, 1, 1);
    STEP(5,  Ar1, Ar0, 1, 1, 1);
    STEP(6,  Ar0, Ar1, 1, 1, 1);
    STEP(7,  Ar1, Ar0, 1, 1, 1);
    STEP(8,  Ar0, Ar1, 1, 1, 1);
    STEP(9,  Ar1, Ar0, 1, 1, 1);
    STEP(10, Ar0, Ar1, 1, 1, 1);
    STEP(11, Ar1, Ar0, 1, 1, 1);
    STEP(12, Ar0, Ar1, 1, 1, 1);
    STEP(13, Ar1, Ar0, 1, 1, 1);
    STEP(14, Ar0, Ar1, 1, 0, 1);   // no gather (K+2=16); drain B(15)
    STEP(15, Ar1, Ar0, 0, 0, 0);   // compute only
#undef STEP

    // epilogue: D col = lane&15 (n), row = g*4 + reg (m)
    #pragma unroll
    for (int fn = 0; fn < 4; ++fn) {
        int n = n0g + wn * 64 + fn * 16 + l15;
        int o = n >> 2, P = (n >> 1) & 1, Q = n & 1;
        float bo = bias[o];
        int ooff = o * 3136 + P * 56 + Q;
        #pragma unroll
        for (int fm = 0; fm < 4; ++fm) {
            int mb = wm * 64 + fm * 16 + (g << 2);
            #pragma unroll
            for (int r = 0; r < 4; ++r)
                out[s_obase[mb + r] + ooff] = acc[fm][fn][r] + bo;
        }
    }
}

extern "C" void kernel_launch(void* const* d_in, const int* in_sizes, int n_in,
                              void* d_out, int out_size, void* d_ws, size_t ws_size,
                              hipStream_t stream)
{
    const float* x = (const float*)d_in[0];
    const float* w = (const float*)d_in[1];
    const float* b = (const float*)d_in[2];
    float* out = (float*)d_out;
    unsigned char* ws = (unsigned char*)d_ws;

    hipLaunchKernelGGL(prep, dim3(2048 + 32), dim3(256), 0, stream, x, w, ws);
    hipLaunchKernelGGL(conv_gemm, dim3(784), dim3(256), 0, stream,
                       (const unsigned short*)ws, ws + BSTG_OFF, b, out);
}